// Round 10
// baseline (128.052 us; speedup 1.0000x reference)
//
#include <hip/hip_runtime.h>
#include <stdint.h>

// ---------------------------------------------------------------------------
// B=2048, F0=40, D=32, LAYER0=LAYER1=128.  Rows r=b*32+d (65536).
//   phase0: h0[r,s] = relu(sum_{i<40,j<40} X[r,i]X[r,j] W0[i,j,s] + b0[s])
//   phase1: d1[r,s] = relu(sum_{i<40,j<64} X[r,i]NH[r,j] W1[i,j,s] + b1[s])
//   out[b,0:64] = sum_d h0[:,64:128]; out[b,64:192] = sum_d d1
//
// Round-19: TWO DESYNCED BLOCKS/CU x 32x32 DATAPATH (r12's structure +
// r16's datapath -- never yet combined).  Evidence: r18 halved VALU (34->21
// measured) and LOST time at 2 waves/SIMD; r17 bv-prefetch null; the ~45%
// stall tracks wave SYNCHRONY, not any single pipe.  All 16 waves of one
// block march in lockstep (same barrier, same code) -> collective stalls
// leave the matrix pipe idle.  r12 (best: 53.3us) was the only 2-block-
// desync round, carrying the worst datapath (16x16, 2x bv, 2x MFMA floor).
// Register ledger now allows the combination: 32x32 Rw2Cw1 datapath = 56
// arch (r16 measured) + 32 acc ~= 88-96 <= the (512,4) 128-reg cap.
//   - block = 128 rows (4 batches), 512 thr = 8 waves (2 rg x 4 sq),
//     wave = 64 rows x 32 cols, acc[2], 4 MFMA 32x32x16/tile.
//   - LDS 51.7KB: Xl 10 + NH 128x68 (17.4; stride 68 -> 2-way max, free)
//     + Wb PERIOD=1 triple buffer 3x8KB = 24.  -> 2 blocks/CU, grid 512.
//   - counted vmcnt: stage = 1 gl_lds16/thread; steady vmcnt(1), raw
//     s_barrier per tile, stage(p+2) post-barrier (m218 mechanism).
//   - W L2 re-reads double: ~9 TB/s agg << 34.5 L2 ceiling; HBM nil.
// Carried: identity-DMA W layout [sq][kh][lane][oct] (conflict-free
// lane-linear b128), symmetrized-triangular W0 (30 tiles), fp16 datapath,
// setprio around MFMA cluster, phase-seam __syncthreads().
// ---------------------------------------------------------------------------

typedef __attribute__((ext_vector_type(8))) _Float16 half8;
typedef __attribute__((ext_vector_type(2))) _Float16 half2v;
typedef __attribute__((ext_vector_type(16))) float f32x16;

#define T0 30        // phase0 tiles after triangular drop
#define T1 80        // phase1 tiles
#define TBUF 4096    // halfwords per Wb buffer (1 tile)
#define NHS 68       // NH row stride in halfwords (136B: 2-way max on b128)

// phase-0 triangular schedule: jc blocks of sizes 2,4,6,8,10 (starts 0,2,6,12,20)
__host__ __device__ constexpr int ic0_of(int t) {
    return (t < 2) ? t : (t < 6) ? (t - 2) : (t < 12) ? (t - 6)
         : (t < 20) ? (t - 12) : (t - 20);
}
__host__ __device__ constexpr int jc0_of(int t) {
    return (t < 2) ? 0 : (t < 6) ? 1 : (t < 12) ? 2 : (t < 20) ? 3 : 4;
}

__device__ __forceinline__ unsigned short f2h(float f) {   // v_cvt_f16_f32, RNE
    return __builtin_bit_cast(unsigned short, (_Float16)f);
}
// async global->LDS DMA, 16 B/lane.  lds dest = (wave-uniform base) + lane*16.
__device__ __forceinline__ void gl_lds16(const unsigned short* g, unsigned short* l) {
    __builtin_amdgcn_global_load_lds(
        (const __attribute__((address_space(1))) unsigned int*)g,
        (__attribute__((address_space(3))) unsigned int*)l,
        16, 0, 0);
}
// A-fragment: broadcast x-scalar (both halves of xs) times 8 packed j-values.
__device__ __forceinline__ uint4 avmul(half2v xs, uint4 jv) {
    uint4 r;
    r.x = __builtin_bit_cast(unsigned int, (half2v)(xs * __builtin_bit_cast(half2v, jv.x)));
    r.y = __builtin_bit_cast(unsigned int, (half2v)(xs * __builtin_bit_cast(half2v, jv.y)));
    r.z = __builtin_bit_cast(unsigned int, (half2v)(xs * __builtin_bit_cast(half2v, jv.z)));
    r.w = __builtin_bit_cast(unsigned int, (half2v)(xs * __builtin_bit_cast(half2v, jv.w)));
    return r;
}

// ---------------------------------------------------------------------------
// Permute W -> Wp[t][ pos = sq*1024 + kh*512 + lane*8 + e ]:
//   s = sq*32 + (lane&31), hb = lane>>5, k = kh*16 + hb*8 + e,
//   i = ic*4 + kh*2 + hb, j = jc*8 + e.
// Exactly the 32x32x16 B-fragment read order (16B/lane, lane-linear) ->
// conflict-free ds_read_b128 AND identity global_load_lds staging.
// Phase0: symmetrized triangular Wsym.  110 blocks x 256 threads.
// ---------------------------------------------------------------------------
__global__ void permute_w_both(const float* __restrict__ W0, const float* __restrict__ W1,
                               unsigned short* __restrict__ Wp0, unsigned short* __restrict__ Wp1)
{
    const int t = blockIdx.x;
    const int tid = threadIdx.x;
    unsigned short outv[16];
    unsigned short* dst;
    if (t < T0) {
        const int ic = ic0_of(t), jc = jc0_of(t);
        #pragma unroll
        for (int q = 0; q < 16; ++q) {
            int pos  = tid * 16 + q;
            int e    = pos & 7, lane = (pos >> 3) & 63;
            int kh   = (pos >> 9) & 1, sq = pos >> 10;
            int s    = sq * 32 + (lane & 31);
            int i    = ic * 4 + kh * 2 + (lane >> 5);
            int j    = jc * 8 + e;
            float v = 0.0f;                                   // i>j: folded into (j,i)
            if (i < j)       v = W0[((size_t)(i * 40 + j)) * 128 + s]
                               + W0[((size_t)(j * 40 + i)) * 128 + s];
            else if (i == j) v = W0[((size_t)(i * 40 + i)) * 128 + s];
            outv[q] = f2h(v);
        }
        dst = Wp0 + (size_t)t * 4096 + tid * 16;
    } else {
        const int tt = t - T0;
        const int jc = tt / 10, ic = tt % 10;
        #pragma unroll
        for (int q = 0; q < 16; ++q) {
            int pos  = tid * 16 + q;
            int e    = pos & 7, lane = (pos >> 3) & 63;
            int kh   = (pos >> 9) & 1, sq = pos >> 10;
            int s    = sq * 32 + (lane & 31);
            int i    = ic * 4 + kh * 2 + (lane >> 5);
            int j    = jc * 8 + e;
            outv[q] = f2h(W1[((size_t)(i * 64 + j)) * 128 + s]);
        }
        dst = Wp1 + (size_t)tt * 4096 + tid * 16;
    }
    *(uint4*)dst       = *(const uint4*)outv;
    *(uint4*)(dst + 8) = *(const uint4*)(outv + 8);
}

// One GEMM phase.  8 waves: rt = wv>>2 (64-row group of 128), sq = wv&3
// (32 cols).  Per tile: 2 bv ds_read_b128 + 2 avmul pairs + 4 MFMA
// 32x32x16 (acc[2]).  PERIOD=1 tile; Wb triple-buffered; one raw barrier
// per tile; steady-state vmcnt(1); stage(p+2) post-barrier.
template<int T, int PHASE>
__device__ __forceinline__ void gemm_phase(
    const unsigned short* __restrict__ Wp,   // [T][4096] fp16, global, read-order layout
    const unsigned short* __restrict__ Jl,   // LDS j-source (Xl or NH)
    int jstride,                             // row stride of Jl in elems
    const unsigned int xk[2][10],            // [kh][ic]: X[row0,i]|X[row1,i]<<16, i=ic*4+kh*2+hb
    unsigned short* Wb,                      // LDS W TRIPLE buffer [3][TBUF]
    f32x16 acc[2], int tid)
{
    const int lane = tid & 63;
    const int wv = tid >> 6;                 // wave id 0..7
    const int rt = wv >> 2;                  // 64-row group (0..1)
    const int sq = wv & 3;                   // s-quarter (32 cols)
    const int c31 = lane & 31;

    const unsigned short* jbase0 = Jl + (rt * 64 + c31) * jstride;
    const unsigned short* jbase1 = jbase0 + 32 * jstride;
    // conflict-free bv base: addr = base + lane*16B (lane-linear)
    const unsigned short* brd = Wb + sq * 1024 + lane * 8;
    // DMA: 512 thr x 16B = 8KB = exactly one tile per call.  Identity
    // layout: per-thread src/dst offset tid*8 halfwords.
    const unsigned short* gsrc = Wp + tid * 8;
    unsigned short* ldst = Wb + tid * 8;

    auto stage = [&](int k) {   // stage tile k -> buf k%3
        gl_lds16(gsrc + (size_t)k * TBUF, ldst + (k % 3) * TBUF);
    };

    stage(0);
    stage(1);

    uint4 jv0, jv1;              // j-octet for row-tile 0 / 1
    #pragma unroll
    for (int p = 0; p < T; ++p) {
        // stage(p) landed?  FIFO vmcnt: <=1 outstanding => only stage(p+1)
        // may remain in flight.  Last tile: drain fully.
        if (p == T - 1) asm volatile("s_waitcnt vmcnt(0)" ::: "memory");
        else            asm volatile("s_waitcnt vmcnt(1)" ::: "memory");
        __builtin_amdgcn_sched_barrier(0);
        __builtin_amdgcn_s_barrier();        // raw: no vmcnt(0) drain
        __builtin_amdgcn_sched_barrier(0);
        if (p + 2 < T) stage(p + 2);         // into buf freed by this barrier
        __builtin_amdgcn_sched_barrier(0);

        const int ic = (PHASE == 0) ? ic0_of(p) : (p % 10);
        const int jc = (PHASE == 0) ? jc0_of(p) : (p / 10);
        const bool rl = (p == 0) ||
            (jc != ((PHASE == 0) ? jc0_of(p - 1) : ((p - 1) / 10)));
        if (rl) {                                        // jv reload (jc changed)
            jv0 = *(const uint4*)(jbase0 + jc * 8);
            jv1 = *(const uint4*)(jbase1 + jc * 8);
        }
        const unsigned short* bper = brd + (p % 3) * TBUF;
        __builtin_amdgcn_s_setprio(1);                   // T5: favor MFMA cluster
        #pragma unroll
        for (int kh = 0; kh < 2; ++kh) {                 // K16 halves of the K32 tile
            uint4 bvv = *(const uint4*)(bper + kh * 512);
            half2v xp = __builtin_bit_cast(half2v, xk[kh][ic]);
            half2v x0 = {xp[0], xp[0]};                  // row-tile 0 x-scalar
            half2v x1 = {xp[1], xp[1]};                  // row-tile 1 x-scalar
            acc[0] = __builtin_amdgcn_mfma_f32_32x32x16_f16(
                __builtin_bit_cast(half8, avmul(x0, jv0)),
                __builtin_bit_cast(half8, bvv), acc[0], 0, 0, 0);
            acc[1] = __builtin_amdgcn_mfma_f32_32x32x16_f16(
                __builtin_bit_cast(half8, avmul(x1, jv1)),
                __builtin_bit_cast(half8, bvv), acc[1], 0, 0, 0);
        }
        __builtin_amdgcn_s_setprio(0);
    }
    // loop exit: all DMAs drained (last tile waited vmcnt(0)); callers
    // place a full __syncthreads() at phase seams.
}

__global__ __launch_bounds__(512, 4)
void fused_two_layer(const float* __restrict__ x,
                     const unsigned short* __restrict__ W0p,
                     const float* __restrict__ b0,
                     const unsigned short* __restrict__ W1p,
                     const float* __restrict__ b1,
                     float* __restrict__ out)
{
    __shared__ __align__(16) unsigned short Xl[128 * 40];    // 10.0 KB
    __shared__ __align__(16) unsigned short NH[128 * NHS];   // 17.0 KB (136B rows)
    __shared__ __align__(16) unsigned short Wb[3 * TBUF];    // 24.0 KB W triple buf
    // total 51.0 KB -> 2 blocks/CU; regs ~88-96 <= 128 cap -> both resident

    const int tid  = threadIdx.x;
    const int lane = tid & 63;
    const int wv   = tid >> 6;
    const int rt   = wv >> 2;           // 64-row group
    const int sq   = wv & 3;            // s-quarter (32 cols)
    const int c31  = lane & 31;
    const int hb   = lane >> 5;

    // ---- stage X: x[4b][i][d] fp32 -> Xl[(bl*32+d)*40 + i] fp16 (RNE) ----
    const float* xblk = x + (size_t)blockIdx.x * (4 * 40 * 32);
    #pragma unroll
    for (int k = 0; k < 10; ++k) {
        int f = 512 * k + tid;          // 0..5119, coalesced
        int bl = f / 1280, rem = f - bl * 1280;
        int i = rem >> 5, d = rem & 31;
        Xl[(bl * 32 + d) * 40 + i] = f2h(xblk[f]);
    }
    __syncthreads();

    // ---- preload this lane's i-scalars: i = ic*4 + kh*2 + hb, rows rt*64+c31
    //      (+32 for row-tile 1), packed lo/hi ----
    unsigned int xk[2][10];
    {
        const unsigned short* xr0 = Xl + (rt * 64 + c31) * 40;
        const unsigned short* xr1 = xr0 + 32 * 40;
        #pragma unroll
        for (int ic = 0; ic < 10; ++ic)
            #pragma unroll
            for (int kh = 0; kh < 2; ++kh) {
                unsigned int u0 = xr0[ic * 4 + kh * 2 + hb];
                unsigned int u1 = xr1[ic * 4 + kh * 2 + hb];
                xk[kh][ic] = u0 | (u1 << 16);
            }
    }

    f32x16 acc[2];
    #pragma unroll
    for (int rtt = 0; rtt < 2; ++rtt)
        #pragma unroll
        for (int rg = 0; rg < 16; ++rg) acc[rtt][rg] = 0.f;

    // ========== phase 0: 30 triangular tiles (Wsym), j from X ==========
    gemm_phase<T0, 0>(W0p, Xl, 40, xk, Wb, acc, tid);

    {   // epilogue 0: sq<2 (s<64) -> NH; sq>=2 -> d-sum -> out[:,0:64]
        float bs = b0[sq * 32 + c31];        // one bias scalar per lane
        if (sq < 2) {
            #pragma unroll
            for (int rtt = 0; rtt < 2; ++rtt)
                #pragma unroll
                for (int rg = 0; rg < 16; ++rg) {
                    int row = rt * 64 + rtt * 32 + (rg & 3) + 8 * (rg >> 2) + 4 * hb;
                    NH[row * NHS + sq * 32 + c31] =
                        f2h(fmaxf(acc[rtt][rg] + bs, 0.0f));
                }
        } else {
            #pragma unroll
            for (int rtt = 0; rtt < 2; ++rtt) {
                float s = 0.f;
                #pragma unroll
                for (int rg = 0; rg < 16; ++rg)
                    s += fmaxf(acc[rtt][rg] + bs, 0.0f);
                s += __shfl_xor(s, 32, 64);  // add other hb's 16 rows
                int bb = blockIdx.x * 4 + rt * 2 + rtt;   // 32-row tile == one batch
                if (lane < 32)
                    out[(size_t)bb * 192 + (sq - 2) * 32 + c31] = s;   // col = s-64
            }
        }
    }
    __syncthreads();   // NH visible to all; drains vmcnt so phase-1 counting
                       // starts clean

    #pragma unroll
    for (int rtt = 0; rtt < 2; ++rtt)
        #pragma unroll
        for (int rg = 0; rg < 16; ++rg) acc[rtt][rg] = 0.f;

    // ========== phase 1: 80 tiles, j from NH ==========
    gemm_phase<T1, 1>(W1p, NH, NHS, xk, Wb, acc, tid);

    {   // epilogue 1: bias+relu; d-sum -> out[:, 64:192]
        float bs = b1[sq * 32 + c31];
        #pragma unroll
        for (int rtt = 0; rtt < 2; ++rtt) {
            float s = 0.f;
            #pragma unroll
            for (int rg = 0; rg < 16; ++rg)
                s += fmaxf(acc[rtt][rg] + bs, 0.0f);
            s += __shfl_xor(s, 32, 64);
            int bb = blockIdx.x * 4 + rt * 2 + rtt;
            if (lane < 32)
                out[(size_t)bb * 192 + 64 + sq * 32 + c31] = s;
        }
    }
}

extern "C" void kernel_launch(void* const* d_in, const int* in_sizes, int n_in,
                              void* d_out, int out_size, void* d_ws, size_t ws_size,
                              hipStream_t stream) {
    const float* x  = (const float*)d_in[0];   // [2048][40][32]
    const float* W0 = (const float*)d_in[1];   // [40][40][128]
    const float* b0 = (const float*)d_in[2];   // [128]
    const float* W1 = (const float*)d_in[3];   // [40][64][128]
    const float* b1 = (const float*)d_in[4];   // [128]
    float* out = (float*)d_out;                // [2048][192]

    unsigned short* W0p = (unsigned short*)d_ws;                          // T0*8192 = 245760 B
    unsigned short* W1p = (unsigned short*)((char*)d_ws + T0 * 4096 * 2); // T1*8192 = 655360 B

    permute_w_both<<<T0 + T1, 256, 0, stream>>>(W0, W1, W0p, W1p);
    fused_two_layer<<<512, 512, 0, stream>>>(x, W0p, b0, W1p, b1, out);
}